// Round 6
// baseline (202.576 us; speedup 1.0000x reference)
//
#include <hip/hip_runtime.h>
#include <hip/hip_bf16.h>

// Problem constants: b=1, n=4 views, f=8 frames, l=256, C=320, H=8, d=40
#define MROWS 8192   // (b*f) * (n*l)
#define CDIM  320
#define QPAD  512    // padded row stride for Q/K/Qi: 8 heads x 64 (cols 40..63 zero)

typedef __attribute__((ext_vector_type(8))) short bf16x8;
typedef __attribute__((ext_vector_type(4))) float f32x4;

__device__ __forceinline__ unsigned bfbits(float x) {  // round-half-up bf16 bits (hi16)
  union { float f; unsigned u; } a; a.f = x;
  return a.u + 0x8000u;
}
__device__ __forceinline__ void splitbf(float x, short& hi, short& lo) {
  unsigned hu = bfbits(x) & 0xffff0000u;
  union { unsigned u; float f; } h; h.u = hu;
  hi = (short)(hu >> 16);
  lo = (short)(bfbits(x - h.f) >> 16);
}
// HW packed f32->bf16 (RNE) via official intrinsic -> v_cvt_pk_bf16_f32
__device__ __forceinline__ unsigned pk_bf16(float a, float b) {
  union { __hip_bfloat162 h2; unsigned u; } cv;
  cv.h2 = __float22bfloat162_rn(float2{a, b});
  return cv.u;   // a in low 16, b in high 16
}

// async global->LDS DMA, 16B/lane; LDS dest = wave-uniform base + lane*16
__device__ __forceinline__ void cp16_g2l(const void* g, void* l) {
  __builtin_amdgcn_global_load_lds(
      (const __attribute__((address_space(1))) void*)g,
      (__attribute__((address_space(3))) void*)l, 16, 0, 0);
}

// rearrange '(b n f) l c -> (b f) (n l) c' row map (involution)
__device__ __forceinline__ int swizzle_row(int r) {
  int ff = r >> 10;
  int t  = r & 1023;
  int nn = t >> 8;
  int ll = t & 255;
  return nn * 2048 + ff * 256 + ll;
}

// ---------------------------------------------------------------------------
// P1: Wc = Wo_i2v @ Wo, fp32, 64x64 tiles, grid (5,5). Tiny (65 MFLOP).
// ---------------------------------------------------------------------------
__global__ __launch_bounds__(256) void wc_kernel(
    const float* __restrict__ Woi, const float* __restrict__ Wo,
    float* __restrict__ Wc)
{
  const int r0 = blockIdx.x * 64, c0 = blockIdx.y * 64;
  __shared__ float As[64][36];
  __shared__ float Bs[32][68];
  const int tid = threadIdx.x, tx = tid & 15, ty = tid >> 4;
  float acc[4][4] = {};

  const int ra = tid >> 3, kq = (tid & 7) * 4;
  const int kb = tid >> 4, cq = (tid & 15) * 4;

  for (int k0 = 0; k0 < 320; k0 += 32) {
    float4 a1 = *(const float4*)(Woi + (size_t)(r0 + ra) * 320 + k0 + kq);
    float4 a2 = *(const float4*)(Woi + (size_t)(r0 + ra + 32) * 320 + k0 + kq);
    float4 b1 = *(const float4*)(Wo + (size_t)(k0 + kb) * 320 + c0 + cq);
    float4 b2 = *(const float4*)(Wo + (size_t)(k0 + kb + 16) * 320 + c0 + cq);
    __syncthreads();
    *(float4*)&As[ra][kq] = a1;
    *(float4*)&As[ra + 32][kq] = a2;
    *(float4*)&Bs[kb][cq] = b1;
    *(float4*)&Bs[kb + 16][cq] = b2;
    __syncthreads();
    #pragma unroll
    for (int kk = 0; kk < 32; ++kk) {
      float4 bv = *(const float4*)&Bs[kk][tx * 4];
      #pragma unroll
      for (int i = 0; i < 4; ++i) {
        float a = As[ty * 4 + i][kk];
        acc[i][0] = fmaf(a, bv.x, acc[i][0]);
        acc[i][1] = fmaf(a, bv.y, acc[i][1]);
        acc[i][2] = fmaf(a, bv.z, acc[i][2]);
        acc[i][3] = fmaf(a, bv.w, acc[i][3]);
      }
    }
  }
  #pragma unroll
  for (int i = 0; i < 4; ++i) {
    float4 v = make_float4(acc[i][0], acc[i][1], acc[i][2], acc[i][3]);
    *(float4*)(Wc + (size_t)(r0 + ty * 4 + i) * 320 + c0 + tx * 4) = v;
  }
}

// ---------------------------------------------------------------------------
// P2: pack/split/zero everything (unchanged).
// ---------------------------------------------------------------------------
__global__ __launch_bounds__(256) void pack_kernel(
    const float* __restrict__ hidden,
    const float* __restrict__ Wq, const float* __restrict__ Wk,
    const float* __restrict__ Wv, const float* __restrict__ Wqi,
    const float* __restrict__ Wo, const float* __restrict__ Wc,
    const float* __restrict__ bo, const float* __restrict__ boi,
    short* __restrict__ Ah, short* __restrict__ Al,
    short* __restrict__ WTh, short* __restrict__ WTl,
    short* __restrict__ WFh, short* __restrict__ WFl,
    float* __restrict__ bc,
    short* __restrict__ Qp, short* __restrict__ Kp, short* __restrict__ Qip,
    float qscale)
{
  const int b = blockIdx.x, tid = threadIdx.x;
  if (b < 64) {
    const int r0 = b * 128;
    for (int e = tid; e < 128 * 80; e += 256) {
      int r = e / 80, cq = (e % 80) * 4;
      float4 x = *(const float4*)(hidden + (size_t)swizzle_row(r0 + r) * 320 + cq);
      union { ushort4 v; short s[4]; } h, l;
      splitbf(x.x, h.s[0], l.s[0]); splitbf(x.y, h.s[1], l.s[1]);
      splitbf(x.z, h.s[2], l.s[2]); splitbf(x.w, h.s[3], l.s[3]);
      *(ushort4*)&Ah[(size_t)(r0 + r) * 320 + cq] = h.v;
      *(ushort4*)&Al[(size_t)(r0 + r) * 320 + cq] = l.v;
    }
  } else if (b < 128) {
    const int t2 = b - 64, wi = t2 >> 4, seg = t2 & 15;
    const float* W = wi == 0 ? Wq : wi == 1 ? Wk : wi == 2 ? Wv : Wqi;
    const float s = (wi == 0 || wi == 3) ? qscale : 1.0f;
    short* th = WTh + (size_t)wi * 320 * 320;
    short* tl = WTl + (size_t)wi * 320 * 320;
    for (int e = tid; e < 20 * 320; e += 256) {
      int n = seg * 20 + e / 320, k = e % 320;
      short hi, lo;
      splitbf(W[(size_t)k * 320 + n] * s, hi, lo);
      th[(size_t)n * 320 + k] = hi;
      tl[(size_t)n * 320 + k] = lo;
    }
  } else if (b < 160) {
    const int t2 = b - 128;
    for (int e = tid; e < 10 * 640; e += 256) {
      int n = t2 * 10 + e / 640, k = e % 640;
      float x = (k < 320) ? Wo[(size_t)k * 320 + n] : Wc[(size_t)(k - 320) * 320 + n];
      short hi, lo;
      splitbf(x, hi, lo);
      WFh[(size_t)n * 640 + k] = hi;
      WFl[(size_t)n * 640 + k] = lo;
    }
  } else if (b < 168) {
    const int n = (b - 160) * 40 + tid;
    if (tid < 40) {
      float s = bo[n];
      for (int j = 0; j < 320; ++j) s = fmaf(boi[j], Wo[(size_t)j * 320 + n], s);
      bc[n] = s;
    }
  } else {
    const int bz = b - 168, buf = bz >> 5, seg = bz & 31;
    short* P = buf == 0 ? Qp : buf == 1 ? Kp : Qip;
    const uint4 z = make_uint4(0, 0, 0, 0);
    for (int e = tid; e < 256 * 24; e += 256) {
      int row = (seg << 8) + (e / 24);
      int cc = e % 24, h = cc / 3, c3 = cc % 3;
      *(uint4*)&P[(size_t)row * QPAD + h * 64 + 40 + c3 * 8] = z;
    }
  }
}

// ---------------------------------------------------------------------------
// Split-bf16 MFMA GEMM, templated over tile shape: M span = 64*MT rows,
// N span = 16*NT cols.
// G1 uses <2,8> = 128x128 (m97-proven best aspect: A re-staged 10x not 20x;
//   B treated as ONE contiguous [1280][320] n-major matrix across the 4
//   weights, since WTh/WTl are laid out wi-contiguously).
// G2 uses <2,4> = 128x64 (grid 320 blocks fills the chip).
// Same K-order as before -> bit-identical numerics.
// ---------------------------------------------------------------------------
template<int MT, int NT>
__global__ __launch_bounds__(256, 3) void mfma_gemm(
    const short* __restrict__ Ah, const short* __restrict__ Al,
    const short* __restrict__ BTh, const short* __restrict__ BTl,
    int K, int mode,
    short* __restrict__ Qp, short* __restrict__ Kp,
    short* __restrict__ Vt, short* __restrict__ Qip,
    float* __restrict__ Of, const float* __restrict__ bias)
{
  const int tid  = threadIdx.x;
  const int wave = tid >> 6;
  const int lane = tid & 63;
  const int quad = lane >> 4;
  const int l16  = lane & 15;
  const int row0 = blockIdx.x * (64 * MT);
  const int nbase = blockIdx.y * (16 * NT);   // global col (mode 0: over 1280)

  __shared__ short Ash[64 * MT][32], Asl[64 * MT][32];
  __shared__ short Bsh[16 * NT][32], Bsl[16 * NT][32];

  f32x4 acc[MT][NT];
  #pragma unroll
  for (int mt = 0; mt < MT; ++mt)
    #pragma unroll
    for (int nt = 0; nt < NT; ++nt) acc[mt][nt] = (f32x4){0.f, 0.f, 0.f, 0.f};

  const int lr = lane >> 2, lc = (lane & 3) * 8;
  const short* gah = Ah + (size_t)(row0 + wave * 16 + lr) * K + lc;
  const short* gal = Al ? Al + (size_t)(row0 + wave * 16 + lr) * K + lc : nullptr;
  const short* gbh = BTh + (size_t)(nbase + wave * 16 + lr) * K + lc;
  const short* gbl = BTl + (size_t)(nbase + wave * 16 + lr) * K + lc;
  short* lah = &Ash[wave * 16][0];
  short* lal = &Asl[wave * 16][0];
  short* lbh = &Bsh[wave * 16][0];
  short* lbl = &Bsl[wave * 16][0];

  for (int k0 = 0; k0 < K; k0 += 32) {
    __syncthreads();
    #pragma unroll
    for (int s = 0; s < MT; ++s) {
      cp16_g2l(gah + (size_t)(s * 64) * K + k0, lah + s * 64 * 32);
      if (Al) cp16_g2l(gal + (size_t)(s * 64) * K + k0, lal + s * 64 * 32);
    }
    #pragma unroll
    for (int s = 0; s < NT / 4; ++s) {
      cp16_g2l(gbh + (size_t)(s * 64) * K + k0, lbh + s * 64 * 32);
      cp16_g2l(gbl + (size_t)(s * 64) * K + k0, lbl + s * 64 * 32);
    }
    __syncthreads();

    bf16x8 afh[MT], afl[MT], bfh[NT], bfl[NT];
    #pragma unroll
    for (int mt = 0; mt < MT; ++mt) {
      afh[mt] = *(const bf16x8*)&Ash[wave * (16 * MT) + mt * 16 + l16][quad * 8];
      if (Al) afl[mt] = *(const bf16x8*)&Asl[wave * (16 * MT) + mt * 16 + l16][quad * 8];
    }
    #pragma unroll
    for (int nt = 0; nt < NT; ++nt) {
      bfh[nt] = *(const bf16x8*)&Bsh[nt * 16 + l16][quad * 8];
      bfl[nt] = *(const bf16x8*)&Bsl[nt * 16 + l16][quad * 8];
    }
    #pragma unroll
    for (int mt = 0; mt < MT; ++mt)
      #pragma unroll
      for (int nt = 0; nt < NT; ++nt) {
        acc[mt][nt] = __builtin_amdgcn_mfma_f32_16x16x32_bf16(afh[mt], bfh[nt], acc[mt][nt], 0, 0, 0);
        acc[mt][nt] = __builtin_amdgcn_mfma_f32_16x16x32_bf16(afh[mt], bfl[nt], acc[mt][nt], 0, 0, 0);
        if (Al)
          acc[mt][nt] = __builtin_amdgcn_mfma_f32_16x16x32_bf16(afl[mt], bfh[nt], acc[mt][nt], 0, 0, 0);
      }
  }

  if (mode == 0) {
    // global col nn in [0,1280): weight wi = nn/320, col-in-weight = nn%320.
    // Each nt-group of 16 cols is 16-aligned and 320%16==0, so wi is uniform
    // within the group.
    #pragma unroll
    for (int mt = 0; mt < MT; ++mt)
      #pragma unroll
      for (int nt = 0; nt < NT; ++nt) {
        const int nn  = nbase + nt * 16 + l16;
        const int wi  = nn / 320;
        const int col = nn - wi * 320;
        const int rowb = row0 + wave * (16 * MT) + mt * 16 + quad * 4;
        if (wi == 2) {
          union { ushort4 v; short s[4]; } pk;
          #pragma unroll
          for (int r = 0; r < 4; ++r) pk.s[r] = (short)(bfbits(acc[mt][nt][r]) >> 16);
          *(ushort4*)&Vt[(size_t)col * MROWS + rowb] = pk.v;
        } else {
          short* Op = wi == 0 ? Qp : wi == 1 ? Kp : Qip;
          const int h    = col / 40;
          const int pcol = h * 64 + (col - h * 40);
          #pragma unroll
          for (int r = 0; r < 4; ++r)
            Op[(size_t)(rowb + r) * QPAD + pcol] = (short)(bfbits(acc[mt][nt][r]) >> 16);
        }
      }
  } else {
    #pragma unroll
    for (int mt = 0; mt < MT; ++mt)
      #pragma unroll
      for (int nt = 0; nt < NT; ++nt) {
        const int col  = nbase + nt * 16 + l16;
        const int rowb = row0 + wave * (16 * MT) + mt * 16 + quad * 4;
        const float bb = bias[col];
        #pragma unroll
        for (int r = 0; r < 4; ++r)
          Of[(size_t)swizzle_row(rowb + r) * CDIM + col] = acc[mt][nt][r] + bb;
      }
  }
}

// ---------------------------------------------------------------------------
// Flash attention, bf16 MFMA — round-0 structure (best measured; zero bank
// conflicts). The 32x32/in-register-P line (rounds 2-4) halved LDS reads but
// regressed; kernel is bound by a VALU+MFMA+LDS stack, not LDS BW.
// grid = (8 qblk, 8 heads, 16 = bf + 8*variant).
// ---------------------------------------------------------------------------
__global__ __launch_bounds__(256, 4) void attn_kernel(
    const short* __restrict__ Qp, const short* __restrict__ Qip,
    const short* __restrict__ Kp, const short* __restrict__ Vtg,
    short* __restrict__ AOh)
{
  const int qblk = blockIdx.x;   // 0..7 (128 q-rows per block)
  const int hh   = blockIdx.y;   // 0..7
  const int zz   = blockIdx.z;   // 0..15
  const int var  = zz >> 3;
  const int bf   = zz & 7;
  const int tid  = threadIdx.x;
  const int wave = tid >> 6;
  const int lane = tid & 63;
  const int quad = lane >> 4;
  const int l16  = lane & 15;

  const short* Q = var ? Qip : Qp;
  const int kvbase = var ? 0 : (bf << 10);
  const int coff = var * 320 + hh * 40;

  __shared__ short Ks[64][64];    // [key][kd], cols 40..63 zero (from Kp pad)
  __shared__ short Vt[48][64];    // [dcol][key]; row 40 = ones, 41..47 zero
  __shared__ short Ps[4][16][68]; // per-wave P buffer (one q-tile at a time)

  // init pad rows once (DMA never writes rows 40..47): row 40 = 1.0 bf16
  if (tid < 64) {
    const int pr = tid >> 3;
    uint4 fill = (pr == 0) ? make_uint4(0x3F803F80u, 0x3F803F80u, 0x3F803F80u, 0x3F803F80u)
                           : make_uint4(0, 0, 0, 0);
    *(uint4*)&Vt[40 + pr][(tid & 7) * 8] = fill;
  }

  // Q B-fragments: 2 q-tiles of 16 rows; n = l16 = q-row, k = quad*8+j
  bf16x8 qf0[2], qf1[2];
  #pragma unroll
  for (int qt = 0; qt < 2; ++qt) {
    const short* qp = Q + (size_t)((bf << 10) + (qblk << 7) + (wave << 5) + (qt << 4) + l16) * QPAD + hh * 64;
    qf0[qt] = *(const bf16x8*)(qp + quad * 8);
    qf1[qt] = *(const bf16x8*)(qp + 32 + quad * 8);
  }

  f32x4 acc[2][3];
  #pragma unroll
  for (int qt = 0; qt < 2; ++qt)
    #pragma unroll
    for (int t = 0; t < 3; ++t) acc[qt][t] = (f32x4){0.f, 0.f, 0.f, 0.f};

  const short* Kb = Kp + (size_t)kvbase * QPAD + hh * 64;
  const short* Vb = Vtg + (size_t)(hh * 40) * MROWS + kvbase;

  // DMA lane geometry: row = base + lane/8, LDS chunk = lane%8,
  // global chunk = (lane%8) ^ ((lane/8)&7)   (XOR swizzle on global side)
  const int lrow = lane >> 3;
  const int gch  = ((lane & 7) ^ (lrow & 7)) * 8;
  const int sw   = l16 & 7;   // row&7 for fragment-read de-swizzle

  for (int s0 = 0; s0 < 1024; s0 += 64) {
    __syncthreads();                 // previous step fully consumed
    #pragma unroll
    for (int j = 0; j < 4; ++j) {
      const int u = j * 4 + wave;    // wave-uniform unit id
      if (u < 8) {                   // K rows u*8 .. u*8+7
        cp16_g2l(Kb + (size_t)(s0 + u * 8 + lrow) * QPAD + gch, &Ks[u * 8][0]);
      } else if (u < 13) {           // V d-rows (u-8)*8 .. (rows 0..39 only)
        cp16_g2l(Vb + (size_t)((u - 8) * 8 + lrow) * MROWS + s0 + gch, &Vt[(u - 8) * 8][0]);
      }
    }
    __syncthreads();                 // vmcnt drained + visible

    // V B-fragments (shared across q-tiles), de-swizzled chunk index
    bf16x8 vf[2][3];
    #pragma unroll
    for (int kh = 0; kh < 2; ++kh)
      #pragma unroll
      for (int t = 0; t < 3; ++t)
        vf[kh][t] = *(const bf16x8*)&Vt[t * 16 + l16][((kh * 4 + quad) ^ sw) * 8];

    #pragma unroll
    for (int qt = 0; qt < 2; ++qt) {
      // ---- QK^T + 2^s + pack, per kt (K frags transient) ----
      #pragma unroll
      for (int kt = 0; kt < 4; ++kt) {
        const short* kr = &Ks[kt * 16 + l16][0];
        bf16x8 kb0 = *(const bf16x8*)(kr + (quad ^ sw) * 8);
        bf16x8 kb1 = *(const bf16x8*)(kr + ((quad + 4) ^ sw) * 8);
        f32x4 st = (f32x4){0.f, 0.f, 0.f, 0.f};
        st = __builtin_amdgcn_mfma_f32_16x16x32_bf16(kb0, qf0[qt], st, 0, 0, 0);
        st = __builtin_amdgcn_mfma_f32_16x16x32_bf16(kb1, qf1[qt], st, 0, 0, 0);
        float p0 = __builtin_amdgcn_exp2f(st[0]);
        float p1 = __builtin_amdgcn_exp2f(st[1]);
        float p2 = __builtin_amdgcn_exp2f(st[2]);
        float p3 = __builtin_amdgcn_exp2f(st[3]);
        uint2 pk;
        pk.x = pk_bf16(p0, p1);
        pk.y = pk_bf16(p2, p3);
        // keys kt*16 + quad*4 + {0..3} for q-row l16 (stride-68 rows)
        *(uint2*)&Ps[wave][l16][kt * 16 + quad * 4] = pk;
      }

      // wave-internal LDS RAW (cross-lane): drain before reading P
      asm volatile("s_waitcnt lgkmcnt(0)" ::: "memory");

      // ---- P @ V (t=2 col 40 accumulates sum(P) via ones-row) ----
      bf16x8 pa0 = *(const bf16x8*)&Ps[wave][l16][quad * 8];
      bf16x8 pa1 = *(const bf16x8*)&Ps[wave][l16][32 + quad * 8];
      #pragma unroll
      for (int t = 0; t < 3; ++t) {
        acc[qt][t] = __builtin_amdgcn_mfma_f32_16x16x32_bf16(pa0, vf[0][t], acc[qt][t], 0, 0, 0);
        acc[qt][t] = __builtin_amdgcn_mfma_f32_16x16x32_bf16(pa1, vf[1][t], acc[qt][t], 0, 0, 0);
      }
      // next qt's Ps writes are safe (DS ops in-order within a wave)
    }
  }

  // ---- epilogue: denom = acc[qt][2][r] at lane l16==8 (col 40) ----
  #pragma unroll
  for (int qt = 0; qt < 2; ++qt) {
    float invr[4];
    #pragma unroll
    for (int r = 0; r < 4; ++r) {
      float d = __shfl(acc[qt][2][r], quad * 16 + 8, 64);  // col-40 lane of this quad
      invr[r] = 1.f / d;
    }

    const int baserow = (bf << 10) + (qblk << 7) + (wave << 5) + (qt << 4) + quad * 4;
    #pragma unroll
    for (int t = 0; t < 3; ++t) {
      int dcol = t * 16 + l16;
      if (dcol < 40) {
        short* op = AOh + (size_t)baserow * 640 + coff + dcol;
        #pragma unroll
        for (int r = 0; r < 4; ++r)
          op[(size_t)r * 640] = (short)(bfbits(acc[qt][t][r] * invr[r]) >> 16);
      }
    }
  }
}

// ---------------------------------------------------------------------------
extern "C" void kernel_launch(void* const* d_in, const int* in_sizes, int n_in,
                              void* d_out, int out_size, void* d_ws, size_t ws_size,
                              hipStream_t stream) {
  const float* hidden  = (const float*)d_in[0];
  const float* Wq      = (const float*)d_in[1];
  const float* Wk      = (const float*)d_in[2];
  const float* Wv      = (const float*)d_in[3];
  const float* Wo      = (const float*)d_in[4];
  const float* bo      = (const float*)d_in[5];
  const float* Wq_i2v  = (const float*)d_in[6];
  const float* Wo_i2v  = (const float*)d_in[7];
  const float* bo_i2v  = (const float*)d_in[8];
  float* out = (float*)d_out;

  const size_t SZ  = (size_t)MROWS * CDIM;    // 2,621,440
  const size_t SZP = (size_t)MROWS * QPAD;    // 4,194,304
  short* Ah  = (short*)d_ws;                  // [8192][320] split hidden (hi)
  short* Al  = Ah + SZ;                       // [8192][320] (lo)
  short* AOh = Ah;                            // attn out [8192][640] — aliases Ah/Al (dead after G1)
  short* Qp  = Al + SZ;                       // [8192][512] padded
  short* Kp  = Qp + SZP;                      // [8192][512] padded
  short* Qip = Kp + SZP;                      // [8192][512] padded
  short* Vt  = Qip + SZP;                     // [328][8192] (rows 320..327 slack)
  short* WTh = Vt + (size_t)328 * MROWS;
  short* WTl = WTh + 409600;
  short* WFh = WTl + 409600;                  // [320][640] transposed [Wo; Wc]
  short* WFl = WFh + 204800;
  float* Wc  = (float*)(WFl + 204800);
  float* bc  = Wc + 102400;

  // (1/sqrt(40)) * log2(e): QK^T scores come out in base-2 scale for exp2
  const float qscale = 0.22811011717177393f;

  // P1: Wc = Wo_i2v @ Wo
  wc_kernel<<<dim3(5, 5), 256, 0, stream>>>(Wo_i2v, Wo, Wc);

  // P2: split/transpose/zero-pad
  pack_kernel<<<dim3(264), 256, 0, stream>>>(
      hidden, Wq, Wk, Wv, Wq_i2v, Wo, Wc, bo, bo_i2v,
      Ah, Al, WTh, WTl, WFh, WFl, bc, Qp, Kp, Qip, qscale);

  // G1: projections (3-term split MFMA), 128x128 tiles over the unified
  // [1280]-col B -> padded Q/K/Qi + V^T. grid (64,10).
  mfma_gemm<2, 8><<<dim3(64, 10), 256, 0, stream>>>(
      Ah, Al, WTh, WTl, 320, 0, Qp, Kp, Vt, Qip, nullptr, nullptr);

  // A: both attentions (base: per-frame KV; i2v: frame-0 KV) -> AOh [8192][640]
  attn_kernel<<<dim3(8, 8, 16), 256, 0, stream>>>(Qp, Qip, Kp, Vt, AOh);

  // G2: out = [base|i2v] @ [Wo; Wo_i2v@Wo] + (bo + bo_i2v@Wo), scattered (2-term)
  mfma_gemm<2, 4><<<dim3(64, 5), 256, 0, stream>>>(
      AOh, nullptr, WFh, WFl, 640, 1, nullptr, nullptr, nullptr, nullptr, out, bc);
}

// Round 7
// 198.296 us; speedup vs baseline: 1.0216x; 1.0216x over previous
//
#include <hip/hip_runtime.h>
#include <hip/hip_bf16.h>

// Problem constants: b=1, n=4 views, f=8 frames, l=256, C=320, H=8, d=40
#define MROWS 8192   // (b*f) * (n*l)
#define CDIM  320
#define QPAD  512    // padded row stride for Q/K/Qi: 8 heads x 64 (cols 40..63 zero)

typedef __attribute__((ext_vector_type(8))) short bf16x8;
typedef __attribute__((ext_vector_type(4))) float f32x4;

__device__ __forceinline__ unsigned bfbits(float x) {  // round-half-up bf16 bits (hi16)
  union { float f; unsigned u; } a; a.f = x;
  return a.u + 0x8000u;
}
__device__ __forceinline__ void splitbf(float x, short& hi, short& lo) {
  unsigned hu = bfbits(x) & 0xffff0000u;
  union { unsigned u; float f; } h; h.u = hu;
  hi = (short)(hu >> 16);
  lo = (short)(bfbits(x - h.f) >> 16);
}
// HW packed f32->bf16 (RNE) via official intrinsic -> v_cvt_pk_bf16_f32
__device__ __forceinline__ unsigned pk_bf16(float a, float b) {
  union { __hip_bfloat162 h2; unsigned u; } cv;
  cv.h2 = __float22bfloat162_rn(float2{a, b});
  return cv.u;   // a in low 16, b in high 16
}

// async global->LDS DMA, 16B/lane; LDS dest = wave-uniform base + lane*16
__device__ __forceinline__ void cp16_g2l(const void* g, void* l) {
  __builtin_amdgcn_global_load_lds(
      (const __attribute__((address_space(1))) void*)g,
      (__attribute__((address_space(3))) void*)l, 16, 0, 0);
}

// rearrange '(b n f) l c -> (b f) (n l) c' row map (involution)
__device__ __forceinline__ int swizzle_row(int r) {
  int ff = r >> 10;
  int t  = r & 1023;
  int nn = t >> 8;
  int ll = t & 255;
  return nn * 2048 + ff * 256 + ll;
}

// ---------------------------------------------------------------------------
// P1: Wc = Wo_i2v @ Wo, fp32, 64x64 tiles, grid (5,5). Tiny (65 MFLOP).
// ---------------------------------------------------------------------------
__global__ __launch_bounds__(256) void wc_kernel(
    const float* __restrict__ Woi, const float* __restrict__ Wo,
    float* __restrict__ Wc)
{
  const int r0 = blockIdx.x * 64, c0 = blockIdx.y * 64;
  __shared__ float As[64][36];
  __shared__ float Bs[32][68];
  const int tid = threadIdx.x, tx = tid & 15, ty = tid >> 4;
  float acc[4][4] = {};

  const int ra = tid >> 3, kq = (tid & 7) * 4;
  const int kb = tid >> 4, cq = (tid & 15) * 4;

  for (int k0 = 0; k0 < 320; k0 += 32) {
    float4 a1 = *(const float4*)(Woi + (size_t)(r0 + ra) * 320 + k0 + kq);
    float4 a2 = *(const float4*)(Woi + (size_t)(r0 + ra + 32) * 320 + k0 + kq);
    float4 b1 = *(const float4*)(Wo + (size_t)(k0 + kb) * 320 + c0 + cq);
    float4 b2 = *(const float4*)(Wo + (size_t)(k0 + kb + 16) * 320 + c0 + cq);
    __syncthreads();
    *(float4*)&As[ra][kq] = a1;
    *(float4*)&As[ra + 32][kq] = a2;
    *(float4*)&Bs[kb][cq] = b1;
    *(float4*)&Bs[kb + 16][cq] = b2;
    __syncthreads();
    #pragma unroll
    for (int kk = 0; kk < 32; ++kk) {
      float4 bv = *(const float4*)&Bs[kk][tx * 4];
      #pragma unroll
      for (int i = 0; i < 4; ++i) {
        float a = As[ty * 4 + i][kk];
        acc[i][0] = fmaf(a, bv.x, acc[i][0]);
        acc[i][1] = fmaf(a, bv.y, acc[i][1]);
        acc[i][2] = fmaf(a, bv.z, acc[i][2]);
        acc[i][3] = fmaf(a, bv.w, acc[i][3]);
      }
    }
  }
  #pragma unroll
  for (int i = 0; i < 4; ++i) {
    float4 v = make_float4(acc[i][0], acc[i][1], acc[i][2], acc[i][3]);
    *(float4*)(Wc + (size_t)(r0 + ty * 4 + i) * 320 + c0 + tx * 4) = v;
  }
}

// ---------------------------------------------------------------------------
// P2: pack/split/zero everything (unchanged).
// ---------------------------------------------------------------------------
__global__ __launch_bounds__(256) void pack_kernel(
    const float* __restrict__ hidden,
    const float* __restrict__ Wq, const float* __restrict__ Wk,
    const float* __restrict__ Wv, const float* __restrict__ Wqi,
    const float* __restrict__ Wo, const float* __restrict__ Wc,
    const float* __restrict__ bo, const float* __restrict__ boi,
    short* __restrict__ Ah, short* __restrict__ Al,
    short* __restrict__ WTh, short* __restrict__ WTl,
    short* __restrict__ WFh, short* __restrict__ WFl,
    float* __restrict__ bc,
    short* __restrict__ Qp, short* __restrict__ Kp, short* __restrict__ Qip,
    float qscale)
{
  const int b = blockIdx.x, tid = threadIdx.x;
  if (b < 64) {
    const int r0 = b * 128;
    for (int e = tid; e < 128 * 80; e += 256) {
      int r = e / 80, cq = (e % 80) * 4;
      float4 x = *(const float4*)(hidden + (size_t)swizzle_row(r0 + r) * 320 + cq);
      union { ushort4 v; short s[4]; } h, l;
      splitbf(x.x, h.s[0], l.s[0]); splitbf(x.y, h.s[1], l.s[1]);
      splitbf(x.z, h.s[2], l.s[2]); splitbf(x.w, h.s[3], l.s[3]);
      *(ushort4*)&Ah[(size_t)(r0 + r) * 320 + cq] = h.v;
      *(ushort4*)&Al[(size_t)(r0 + r) * 320 + cq] = l.v;
    }
  } else if (b < 128) {
    const int t2 = b - 64, wi = t2 >> 4, seg = t2 & 15;
    const float* W = wi == 0 ? Wq : wi == 1 ? Wk : wi == 2 ? Wv : Wqi;
    const float s = (wi == 0 || wi == 3) ? qscale : 1.0f;
    short* th = WTh + (size_t)wi * 320 * 320;
    short* tl = WTl + (size_t)wi * 320 * 320;
    for (int e = tid; e < 20 * 320; e += 256) {
      int n = seg * 20 + e / 320, k = e % 320;
      short hi, lo;
      splitbf(W[(size_t)k * 320 + n] * s, hi, lo);
      th[(size_t)n * 320 + k] = hi;
      tl[(size_t)n * 320 + k] = lo;
    }
  } else if (b < 160) {
    const int t2 = b - 128;
    for (int e = tid; e < 10 * 640; e += 256) {
      int n = t2 * 10 + e / 640, k = e % 640;
      float x = (k < 320) ? Wo[(size_t)k * 320 + n] : Wc[(size_t)(k - 320) * 320 + n];
      short hi, lo;
      splitbf(x, hi, lo);
      WFh[(size_t)n * 640 + k] = hi;
      WFl[(size_t)n * 640 + k] = lo;
    }
  } else if (b < 168) {
    const int n = (b - 160) * 40 + tid;
    if (tid < 40) {
      float s = bo[n];
      for (int j = 0; j < 320; ++j) s = fmaf(boi[j], Wo[(size_t)j * 320 + n], s);
      bc[n] = s;
    }
  } else {
    const int bz = b - 168, buf = bz >> 5, seg = bz & 31;
    short* P = buf == 0 ? Qp : buf == 1 ? Kp : Qip;
    const uint4 z = make_uint4(0, 0, 0, 0);
    for (int e = tid; e < 256 * 24; e += 256) {
      int row = (seg << 8) + (e / 24);
      int cc = e % 24, h = cc / 3, c3 = cc % 3;
      *(uint4*)&P[(size_t)row * QPAD + h * 64 + 40 + c3 * 8] = z;
    }
  }
}

// ---------------------------------------------------------------------------
// Split-bf16 MFMA GEMM, templated over tile shape (unchanged from round 6).
// ---------------------------------------------------------------------------
template<int MT, int NT>
__global__ __launch_bounds__(256, 3) void mfma_gemm(
    const short* __restrict__ Ah, const short* __restrict__ Al,
    const short* __restrict__ BTh, const short* __restrict__ BTl,
    int K, int mode,
    short* __restrict__ Qp, short* __restrict__ Kp,
    short* __restrict__ Vt, short* __restrict__ Qip,
    float* __restrict__ Of, const float* __restrict__ bias)
{
  const int tid  = threadIdx.x;
  const int wave = tid >> 6;
  const int lane = tid & 63;
  const int quad = lane >> 4;
  const int l16  = lane & 15;
  const int row0 = blockIdx.x * (64 * MT);
  const int nbase = blockIdx.y * (16 * NT);   // global col (mode 0: over 1280)

  __shared__ short Ash[64 * MT][32], Asl[64 * MT][32];
  __shared__ short Bsh[16 * NT][32], Bsl[16 * NT][32];

  f32x4 acc[MT][NT];
  #pragma unroll
  for (int mt = 0; mt < MT; ++mt)
    #pragma unroll
    for (int nt = 0; nt < NT; ++nt) acc[mt][nt] = (f32x4){0.f, 0.f, 0.f, 0.f};

  const int lr = lane >> 2, lc = (lane & 3) * 8;
  const short* gah = Ah + (size_t)(row0 + wave * 16 + lr) * K + lc;
  const short* gal = Al ? Al + (size_t)(row0 + wave * 16 + lr) * K + lc : nullptr;
  const short* gbh = BTh + (size_t)(nbase + wave * 16 + lr) * K + lc;
  const short* gbl = BTl + (size_t)(nbase + wave * 16 + lr) * K + lc;
  short* lah = &Ash[wave * 16][0];
  short* lal = &Asl[wave * 16][0];
  short* lbh = &Bsh[wave * 16][0];
  short* lbl = &Bsl[wave * 16][0];

  for (int k0 = 0; k0 < K; k0 += 32) {
    __syncthreads();
    #pragma unroll
    for (int s = 0; s < MT; ++s) {
      cp16_g2l(gah + (size_t)(s * 64) * K + k0, lah + s * 64 * 32);
      if (Al) cp16_g2l(gal + (size_t)(s * 64) * K + k0, lal + s * 64 * 32);
    }
    #pragma unroll
    for (int s = 0; s < NT / 4; ++s) {
      cp16_g2l(gbh + (size_t)(s * 64) * K + k0, lbh + s * 64 * 32);
      cp16_g2l(gbl + (size_t)(s * 64) * K + k0, lbl + s * 64 * 32);
    }
    __syncthreads();

    bf16x8 afh[MT], afl[MT], bfh[NT], bfl[NT];
    #pragma unroll
    for (int mt = 0; mt < MT; ++mt) {
      afh[mt] = *(const bf16x8*)&Ash[wave * (16 * MT) + mt * 16 + l16][quad * 8];
      if (Al) afl[mt] = *(const bf16x8*)&Asl[wave * (16 * MT) + mt * 16 + l16][quad * 8];
    }
    #pragma unroll
    for (int nt = 0; nt < NT; ++nt) {
      bfh[nt] = *(const bf16x8*)&Bsh[nt * 16 + l16][quad * 8];
      bfl[nt] = *(const bf16x8*)&Bsl[nt * 16 + l16][quad * 8];
    }
    #pragma unroll
    for (int mt = 0; mt < MT; ++mt)
      #pragma unroll
      for (int nt = 0; nt < NT; ++nt) {
        acc[mt][nt] = __builtin_amdgcn_mfma_f32_16x16x32_bf16(afh[mt], bfh[nt], acc[mt][nt], 0, 0, 0);
        acc[mt][nt] = __builtin_amdgcn_mfma_f32_16x16x32_bf16(afh[mt], bfl[nt], acc[mt][nt], 0, 0, 0);
        if (Al)
          acc[mt][nt] = __builtin_amdgcn_mfma_f32_16x16x32_bf16(afl[mt], bfh[nt], acc[mt][nt], 0, 0, 0);
      }
  }

  if (mode == 0) {
    #pragma unroll
    for (int mt = 0; mt < MT; ++mt)
      #pragma unroll
      for (int nt = 0; nt < NT; ++nt) {
        const int nn  = nbase + nt * 16 + l16;
        const int wi  = nn / 320;
        const int col = nn - wi * 320;
        const int rowb = row0 + wave * (16 * MT) + mt * 16 + quad * 4;
        if (wi == 2) {
          union { ushort4 v; short s[4]; } pk;
          #pragma unroll
          for (int r = 0; r < 4; ++r) pk.s[r] = (short)(bfbits(acc[mt][nt][r]) >> 16);
          *(ushort4*)&Vt[(size_t)col * MROWS + rowb] = pk.v;
        } else {
          short* Op = wi == 0 ? Qp : wi == 1 ? Kp : Qip;
          const int h    = col / 40;
          const int pcol = h * 64 + (col - h * 40);
          #pragma unroll
          for (int r = 0; r < 4; ++r)
            Op[(size_t)(rowb + r) * QPAD + pcol] = (short)(bfbits(acc[mt][nt][r]) >> 16);
        }
      }
  } else {
    #pragma unroll
    for (int mt = 0; mt < MT; ++mt)
      #pragma unroll
      for (int nt = 0; nt < NT; ++nt) {
        const int col  = nbase + nt * 16 + l16;
        const int rowb = row0 + wave * (16 * MT) + mt * 16 + quad * 4;
        const float bb = bias[col];
        #pragma unroll
        for (int r = 0; r < 4; ++r)
          Of[(size_t)swizzle_row(rowb + r) * CDIM + col] = acc[mt][nt][r] + bb;
      }
  }
}

// ---------------------------------------------------------------------------
// Flash attention, round 7: round-0 algorithm, 8-WAVE BLOCKS (512 threads).
// Same 128 q-rows/block (each wave owns 16 rows; qt loop gone), same DMA
// geometry, same LDS layout (Ks 8K + Vt 6K + Ps[8] 17.4K = 31.4 KB), same
// numerics. 1024 blocks -> 4 blocks/CU x 8 waves = 32 waves/CU (was 16):
// doubles the wave pool that hides the per-step barrier/vmcnt drains (m114
// overlap). VGPR shrinks (acc 24->12 f32) to fit the (512,8) 64-VGPR cap.
// grid = (8 qblk, 8 heads, 16 = bf + 8*variant).
// ---------------------------------------------------------------------------
__global__ __launch_bounds__(512, 8) void attn_kernel(
    const short* __restrict__ Qp, const short* __restrict__ Qip,
    const short* __restrict__ Kp, const short* __restrict__ Vtg,
    short* __restrict__ AOh)
{
  const int qblk = blockIdx.x;   // 0..7 (128 q-rows per block)
  const int hh   = blockIdx.y;   // 0..7
  const int zz   = blockIdx.z;   // 0..15
  const int var  = zz >> 3;
  const int bf   = zz & 7;
  const int tid  = threadIdx.x;
  const int wave = tid >> 6;     // 0..7
  const int lane = tid & 63;
  const int quad = lane >> 4;
  const int l16  = lane & 15;

  const short* Q = var ? Qip : Qp;
  const int kvbase = var ? 0 : (bf << 10);
  const int coff = var * 320 + hh * 40;

  __shared__ short Ks[64][64];    // [key][kd], cols 40..63 zero (from Kp pad)
  __shared__ short Vt[48][64];    // [dcol][key]; row 40 = ones, 41..47 zero
  __shared__ short Ps[8][16][68]; // per-wave P buffer

  // init pad rows once (DMA never writes rows 40..47): row 40 = 1.0 bf16
  if (tid < 64) {
    const int pr = tid >> 3;
    uint4 fill = (pr == 0) ? make_uint4(0x3F803F80u, 0x3F803F80u, 0x3F803F80u, 0x3F803F80u)
                           : make_uint4(0, 0, 0, 0);
    *(uint4*)&Vt[40 + pr][(tid & 7) * 8] = fill;
  }

  // Q B-fragments: wave owns 16 q-rows; n = l16 = q-row, k = quad*8+j
  bf16x8 qf0, qf1;
  {
    const short* qp = Q + (size_t)((bf << 10) + (qblk << 7) + (wave << 4) + l16) * QPAD + hh * 64;
    qf0 = *(const bf16x8*)(qp + quad * 8);
    qf1 = *(const bf16x8*)(qp + 32 + quad * 8);
  }

  f32x4 acc[3];
  #pragma unroll
  for (int t = 0; t < 3; ++t) acc[t] = (f32x4){0.f, 0.f, 0.f, 0.f};

  const short* Kb = Kp + (size_t)kvbase * QPAD + hh * 64;
  const short* Vb = Vtg + (size_t)(hh * 40) * MROWS + kvbase;

  // DMA lane geometry: row = base + lane/8, LDS chunk = lane%8,
  // global chunk = (lane%8) ^ ((lane/8)&7)   (XOR swizzle on global side)
  const int lrow = lane >> 3;
  const int gch  = ((lane & 7) ^ (lrow & 7)) * 8;
  const int sw   = l16 & 7;   // row&7 for fragment-read de-swizzle

  for (int s0 = 0; s0 < 1024; s0 += 64) {
    __syncthreads();                 // previous step fully consumed
    #pragma unroll
    for (int j = 0; j < 2; ++j) {
      const int u = j * 8 + wave;    // wave-uniform unit id, 0..15
      if (u < 8) {                   // K rows u*8 .. u*8+7
        cp16_g2l(Kb + (size_t)(s0 + u * 8 + lrow) * QPAD + gch, &Ks[u * 8][0]);
      } else if (u < 13) {           // V d-rows (u-8)*8 .. (rows 0..39 only)
        cp16_g2l(Vb + (size_t)((u - 8) * 8 + lrow) * MROWS + s0 + gch, &Vt[(u - 8) * 8][0]);
      }
    }
    __syncthreads();                 // vmcnt drained + visible

    // V B-fragments, de-swizzled chunk index
    bf16x8 vf[2][3];
    #pragma unroll
    for (int kh = 0; kh < 2; ++kh)
      #pragma unroll
      for (int t = 0; t < 3; ++t)
        vf[kh][t] = *(const bf16x8*)&Vt[t * 16 + l16][((kh * 4 + quad) ^ sw) * 8];

    // ---- QK^T + 2^s + pack, per kt (K frags transient) ----
    #pragma unroll
    for (int kt = 0; kt < 4; ++kt) {
      const short* kr = &Ks[kt * 16 + l16][0];
      bf16x8 kb0 = *(const bf16x8*)(kr + (quad ^ sw) * 8);
      bf16x8 kb1 = *(const bf16x8*)(kr + ((quad + 4) ^ sw) * 8);
      f32x4 st = (f32x4){0.f, 0.f, 0.f, 0.f};
      st = __builtin_amdgcn_mfma_f32_16x16x32_bf16(kb0, qf0, st, 0, 0, 0);
      st = __builtin_amdgcn_mfma_f32_16x16x32_bf16(kb1, qf1, st, 0, 0, 0);
      float p0 = __builtin_amdgcn_exp2f(st[0]);
      float p1 = __builtin_amdgcn_exp2f(st[1]);
      float p2 = __builtin_amdgcn_exp2f(st[2]);
      float p3 = __builtin_amdgcn_exp2f(st[3]);
      uint2 pk;
      pk.x = pk_bf16(p0, p1);
      pk.y = pk_bf16(p2, p3);
      // keys kt*16 + quad*4 + {0..3} for q-row l16 (stride-68 rows)
      *(uint2*)&Ps[wave][l16][kt * 16 + quad * 4] = pk;
    }

    // wave-internal LDS RAW (cross-lane): drain before reading P
    asm volatile("s_waitcnt lgkmcnt(0)" ::: "memory");

    // ---- P @ V (t=2 col 40 accumulates sum(P) via ones-row) ----
    bf16x8 pa0 = *(const bf16x8*)&Ps[wave][l16][quad * 8];
    bf16x8 pa1 = *(const bf16x8*)&Ps[wave][l16][32 + quad * 8];
    #pragma unroll
    for (int t = 0; t < 3; ++t) {
      acc[t] = __builtin_amdgcn_mfma_f32_16x16x32_bf16(pa0, vf[0][t], acc[t], 0, 0, 0);
      acc[t] = __builtin_amdgcn_mfma_f32_16x16x32_bf16(pa1, vf[1][t], acc[t], 0, 0, 0);
    }
  }

  // ---- epilogue: denom = acc[2][r] at lane l16==8 (col 40) ----
  float invr[4];
  #pragma unroll
  for (int r = 0; r < 4; ++r) {
    float d = __shfl(acc[2][r], quad * 16 + 8, 64);  // col-40 lane of this quad
    invr[r] = 1.f / d;
  }

  const int baserow = (bf << 10) + (qblk << 7) + (wave << 4) + quad * 4;
  #pragma unroll
  for (int t = 0; t < 3; ++t) {
    int dcol = t * 16 + l16;
    if (dcol < 40) {
      short* op = AOh + (size_t)baserow * 640 + coff + dcol;
      #pragma unroll
      for (int r = 0; r < 4; ++r)
        op[(size_t)r * 640] = (short)(bfbits(acc[t][r] * invr[r]) >> 16);
    }
  }
}

// ---------------------------------------------------------------------------
extern "C" void kernel_launch(void* const* d_in, const int* in_sizes, int n_in,
                              void* d_out, int out_size, void* d_ws, size_t ws_size,
                              hipStream_t stream) {
  const float* hidden  = (const float*)d_in[0];
  const float* Wq      = (const float*)d_in[1];
  const float* Wk      = (const float*)d_in[2];
  const float* Wv      = (const float*)d_in[3];
  const float* Wo      = (const float*)d_in[4];
  const float* bo      = (const float*)d_in[5];
  const float* Wq_i2v  = (const float*)d_in[6];
  const float* Wo_i2v  = (const float*)d_in[7];
  const float* bo_i2v  = (const float*)d_in[8];
  float* out = (float*)d_out;

  const size_t SZ  = (size_t)MROWS * CDIM;    // 2,621,440
  const size_t SZP = (size_t)MROWS * QPAD;    // 4,194,304
  short* Ah  = (short*)d_ws;                  // [8192][320] split hidden (hi)
  short* Al  = Ah + SZ;                       // [8192][320] (lo)
  short* AOh = Ah;                            // attn out [8192][640] — aliases Ah/Al (dead after G1)
  short* Qp  = Al + SZ;                       // [8192][512] padded
  short* Kp  = Qp + SZP;                      // [8192][512] padded
  short* Qip = Kp + SZP;                      // [8192][512] padded
  short* Vt  = Qip + SZP;                     // [328][8192] (rows 320..327 slack)
  short* WTh = Vt + (size_t)328 * MROWS;
  short* WTl = WTh + 409600;
  short* WFh = WTl + 409600;                  // [320][640] transposed [Wo; Wc]
  short* WFl = WFh + 204800;
  float* Wc  = (float*)(WFl + 204800);
  float* bc  = Wc + 102400;

  // (1/sqrt(40)) * log2(e): QK^T scores come out in base-2 scale for exp2
  const float qscale = 0.22811011717177393f;

  // P1: Wc = Wo_i2v @ Wo
  wc_kernel<<<dim3(5, 5), 256, 0, stream>>>(Wo_i2v, Wo, Wc);

  // P2: split/transpose/zero-pad
  pack_kernel<<<dim3(264), 256, 0, stream>>>(
      hidden, Wq, Wk, Wv, Wq_i2v, Wo, Wc, bo, bo_i2v,
      Ah, Al, WTh, WTl, WFh, WFl, bc, Qp, Kp, Qip, qscale);

  // G1: projections (3-term split MFMA), 128x128 tiles over unified 1280-col B
  mfma_gemm<2, 8><<<dim3(64, 10), 256, 0, stream>>>(
      Ah, Al, WTh, WTl, 320, 0, Qp, Kp, Vt, Qip, nullptr, nullptr);

  // A: both attentions (base: per-frame KV; i2v: frame-0 KV) -> AOh [8192][640]
  attn_kernel<<<dim3(8, 8, 16), 512, 0, stream>>>(Qp, Qip, Kp, Vt, AOh);

  // G2: out = [base|i2v] @ [Wo; Wo_i2v@Wo] + (bo + bo_i2v@Wo), scattered (2-term)
  mfma_gemm<2, 4><<<dim3(64, 5), 256, 0, stream>>>(
      AOh, nullptr, WFh, WFl, 640, 1, nullptr, nullptr, nullptr, nullptr, out, bc);
}